// Round 14
// baseline (319.624 us; speedup 1.0000x reference)
//
#include <hip/hip_runtime.h>
#include <hip/hip_bf16.h>

// ---------------------------------------------------------------------------
// attention via: E = exp(QK^T/32) (bf16), inv[r] = 1/sum_k E[r,k], O = inv*E*V.
// r14: BOTH GEMMs at BM=BN=128, LDS 64KB -> 2 BLOCKS/CU (16 waves). Per-CU
// aggregate demands identical to the 256-tile version; the lever is m114
// cross-block overlap (two independent barrier groups keep LDS+MFMA pipes
// fed). 4 phases per 2-K-tile iter; staging into just-dead regions:
//   ph0: DS(b0 mh0+B); BAR WAITL; ISSUE_B(t+1); MMA; BAR
//   ph1: DS(b0 mh1);   BAR WAITL; ISSUE_A(t+2); MMA; VM(2); BAR
//   ph2: DS(b1 mh0+B); BAR WAITL; ISSUE_B(t+2); MMA; BAR
//   ph3: DS(b1 mh1);   BAR WAITL; ISSUE_A(t+3); MMA; VM(2); BAR
// A-leads 2 phases (HBM-streamed operand), B 1 phase (L2/L3-resident).
// VM(2) counted; never drains mid-loop. T2 XOR swizzle (0-conflict family),
// T5 setprio, de-pinned sync (r13). Decodes: GEMM1 4096 wgs, 8bm x 8bn
// subchunks (4MB L2 ws); GEMM2 512 wgs, bm-stripe per XCD.
// ws: [0,128MB)=E ; [128,144MB)=V^T ; [144,148MB)=partials[8192][64] ; inv.
// ---------------------------------------------------------------------------

typedef __bf16 bf16x8 __attribute__((ext_vector_type(8)));
typedef float f32x4 __attribute__((ext_vector_type(4)));
typedef const __attribute__((address_space(1))) unsigned int* as1p;
typedef __attribute__((address_space(3))) unsigned int* as3p;
typedef unsigned short u16;

__device__ __forceinline__ u16 f2bf(float x) {
  unsigned u = __float_as_uint(x);
  u += 0x7fffu + ((u >> 16) & 1u);
  return (u16)(u >> 16);
}
__device__ __forceinline__ float bf2f(u16 b) { return __uint_as_float(((unsigned)b) << 16); }
__device__ __forceinline__ unsigned pack2(float lo, float hi) {
  return (unsigned)f2bf(lo) | ((unsigned)f2bf(hi) << 16);
}

#define BARX()   __builtin_amdgcn_s_barrier()
#define WAITL()  asm volatile("s_waitcnt lgkmcnt(0)")
#define WAITV(n) asm volatile("s_waitcnt vmcnt(" #n ")")

// --------------------------- f32 -> bf16 convert ---------------------------
__global__ __launch_bounds__(256) void cvt_bf16(const float* __restrict__ in,
                                                unsigned short* __restrict__ out) {
  const size_t i = (size_t)blockIdx.x * 256 + threadIdx.x;
  const float4* p = (const float4*)in + i * 2;
  float4 a = p[0], b = p[1];
  uint4 o;
  o.x = pack2(a.x, a.y);
  o.y = pack2(a.z, a.w);
  o.z = pack2(b.x, b.y);
  o.w = pack2(b.z, b.w);
  ((uint4*)out)[i] = o;
}

// ------------- V [8192,1024] f32 -> V^T [1024,8192] bf16 -------------------
__global__ __launch_bounds__(256) void transpose_bf16(const float* __restrict__ V,
                                                      unsigned short* __restrict__ VT) {
  __shared__ float t[64][65];
  const int rb = blockIdx.x * 64;
  const int cb = blockIdx.y * 64;
  const int tid = threadIdx.x;
#pragma unroll
  for (int it = 0; it < 4; ++it) {
    int r = it * 16 + (tid >> 4);
    int c = (tid & 15) * 4;
    float4 x = *(const float4*)(V + (size_t)(rb + r) * 1024 + cb + c);
    t[r][c] = x.x; t[r][c + 1] = x.y; t[r][c + 2] = x.z; t[r][c + 3] = x.w;
  }
  __syncthreads();
  const int j = tid & 63;
  const int c0 = (tid >> 6) * 16;
#pragma unroll
  for (int i = 0; i < 16; ++i) {
    int c = c0 + i;
    VT[(size_t)(cb + c) * 8192 + rb + j] = f2bf(t[j][c]);
  }
}

// --------------- 128x128 NT GEMM, 2 blocks/CU, 4-phase pipeline ------------
// C[M,N](ldc) = A[M,K]*B[N,K]^T. 512 threads, 8 waves (2M x 4N), per-wave
// 64x32. OUTMODE 0: C=bf16 exp(acc*scale) + partials[8192][64] (LDS-reduced
// across the 4 col-waves). OUTMODE 1: C=f32 acc*inv[row].
template <int OUTMODE, int DEC>
__global__ __launch_bounds__(512, 4) void gemm2b(const u16* __restrict__ A,
                                                 const u16* __restrict__ B,
                                                 void* __restrict__ Cv,
                                                 const float* __restrict__ inv,
                                                 float* __restrict__ partials,
                                                 int K, int ldc, float scale) {
  constexpr int ABUF = 16384;          // 128 rows x 128B
  constexpr int BUFSZ = 32768;         // A + B
  __shared__ __align__(1024) char smem[2 * BUFSZ];

  const int tid = threadIdx.x;
  const int lane = tid & 63, wave = tid >> 6;
  const int wr = wave >> 2, wc = wave & 3;
  const int lan15 = lane & 15, g = lane >> 4, l7 = lane & 7;

  // T1: bijective XCD swizzle (nwg % 8 == 0 at both call sites)
  const int nwg = gridDim.x;
  const int wg = (blockIdx.x & 7) * (nwg >> 3) + (blockIdx.x >> 3);
  int bm0, bn0;
  if constexpr (DEC == 0) {
    // 4096 wgs: chunk 512/XCD = 8bm x 64bn; subchunk 64 = 8bm x 8bn (4MB L2)
    const int chunk = wg >> 9;
    const int r9 = wg & 511;
    const int sub = r9 >> 6, win = r9 & 63;
    bm0 = (chunk * 8 + (win >> 3)) * 128;
    bn0 = (sub * 8 + (win & 7)) * 128;
  } else {
    // 512 wgs: chunk 64/XCD = 8bm x 8bn (bn fastest -> stripe shares L2)
    const int chunk = wg >> 6;
    const int win = wg & 63;
    bm0 = (chunk * 8 + (win >> 3)) * 128;
    bn0 = (win & 7) * 128;
  }

  // staging: thread -> row (tid>>3) in 64-row batch j, swizzled col-block
  const int sr = tid >> 3;
  const int scb = ((tid & 7) ^ (sr & 7)) * 8;
  const u16* Ags = A + (size_t)(bm0 + sr) * K + scb;
  const u16* Bgs = B + (size_t)(bn0 + sr) * K + scb;

  // fragment-read swizzled 16B-slot offsets
  const int sa0 = ((0 + g) ^ l7) * 16;
  const int sa1 = ((4 + g) ^ l7) * 16;
  const int abase = (wr * 64 + lan15) * 128;
  const int bbase = ABUF + (wc * 32 + lan15) * 128;

  f32x4 acc[4][2];
#pragma unroll
  for (int m = 0; m < 4; ++m)
#pragma unroll
    for (int n = 0; n < 2; ++n) acc[m][n] = f32x4{0.f, 0.f, 0.f, 0.f};

  const int nt = K >> 6;
  const int niter = nt >> 1;

  auto IA = [&](int t) {  // 2 loads: batches j=0,1 (rows 0-63, 64-127)
    char* bb = smem + (t & 1) * BUFSZ;
    const size_t ko = (size_t)t * 64;
    __builtin_amdgcn_global_load_lds((as1p)(Ags + ko),
                                     (as3p)(bb + tid * 16), 16, 0, 0);
    __builtin_amdgcn_global_load_lds((as1p)(Ags + (size_t)64 * K + ko),
                                     (as3p)(bb + 8192 + tid * 16), 16, 0, 0);
  };
  auto IB = [&](int t) {
    char* bb = smem + (t & 1) * BUFSZ + ABUF;
    const size_t ko = (size_t)t * 64;
    __builtin_amdgcn_global_load_lds((as1p)(Bgs + ko),
                                     (as3p)(bb + tid * 16), 16, 0, 0);
    __builtin_amdgcn_global_load_lds((as1p)(Bgs + (size_t)64 * K + ko),
                                     (as3p)(bb + 8192 + tid * 16), 16, 0, 0);
  };

  bf16x8 a[2][2], b[2][2];
  auto DS_A = [&](int bb, int mh) {
#pragma unroll
    for (int m = 0; m < 2; ++m) {
      a[m][0] = *(const bf16x8*)(smem + bb + abase + (mh * 2 + m) * 2048 + sa0);
      a[m][1] = *(const bf16x8*)(smem + bb + abase + (mh * 2 + m) * 2048 + sa1);
    }
  };
  auto DS_B = [&](int bb) {
#pragma unroll
    for (int n = 0; n < 2; ++n) {
      b[n][0] = *(const bf16x8*)(smem + bb + bbase + n * 2048 + sa0);
      b[n][1] = *(const bf16x8*)(smem + bb + bbase + n * 2048 + sa1);
    }
  };
  auto MMA = [&](int mh) {
    __builtin_amdgcn_s_setprio(1);
#pragma unroll
    for (int m = 0; m < 2; ++m)
#pragma unroll
      for (int n = 0; n < 2; ++n)
#pragma unroll
        for (int ks = 0; ks < 2; ++ks)
          acc[mh * 2 + m][n] = __builtin_amdgcn_mfma_f32_16x16x32_bf16(
              a[m][ks], b[n][ks], acc[mh * 2 + m][n], 0, 0, 0);
    __builtin_amdgcn_s_setprio(0);
  };

  // prologue: tile0 + A(1); certify tile0 (A(1) stays in flight)
  IA(0); IB(0); IA(1);
  WAITV(2);
  BARX();

  for (int i = 0; i < niter; ++i) {
    const int t0 = 2 * i;
    const bool more = (t0 + 2 < nt);

    // ph0: buf0 mh0 (+B); stage B(t0+1) after reads certified
    DS_A(0, 0); DS_B(0);
    BARX(); WAITL();
    IB(t0 + 1);
    MMA(0);
    BARX();

    // ph1: buf0 mh1; stage A(t0+2) into dead buf0-A; certify t0+1
    DS_A(0, 1);
    BARX(); WAITL();
    if (more) { IA(t0 + 2); MMA(1); WAITV(2); }
    else      { MMA(1); WAITV(0); }
    BARX();

    // ph2: buf1 mh0 (+B); stage B(t0+2)
    DS_A(BUFSZ, 0); DS_B(BUFSZ);
    BARX(); WAITL();
    if (more) IB(t0 + 2);
    MMA(0);
    BARX();

    // ph3: buf1 mh1; stage A(t0+3); certify t0+2
    DS_A(BUFSZ, 1);
    BARX(); WAITL();
    if (more) { IA(t0 + 3); MMA(1); WAITV(2); }
    else      { MMA(1); }
    BARX();
  }

  // ---- epilogue. C/D map: col = lane&15, row = (lane>>4)*4 + reg
  const int c0 = bn0 + wc * 32 + lan15;
  if constexpr (OUTMODE == 0) {
    u16* C = (u16*)Cv;
    float* red = (float*)smem;  // [128 rows][4 wc]
    float part_rows[4][4];
#pragma unroll
    for (int m = 0; m < 4; ++m)
#pragma unroll
      for (int r = 0; r < 4; ++r) {
        const int row = bm0 + wr * 64 + m * 16 + g * 4 + r;
        float part = 0.f;
#pragma unroll
        for (int n = 0; n < 2; ++n) {
          float v = __expf(acc[m][n][r] * scale);
          C[(size_t)row * ldc + c0 + n * 16] = f2bf(v);
          part += v;
        }
        part += __shfl_xor(part, 1, 64);
        part += __shfl_xor(part, 2, 64);
        part += __shfl_xor(part, 4, 64);
        part += __shfl_xor(part, 8, 64);
        part_rows[m][r] = part;
      }
    BARX();  // all waves done with smem tiles
#pragma unroll
    for (int m = 0; m < 4; ++m)
#pragma unroll
      for (int r = 0; r < 4; ++r)
        if (lan15 == 0)
          red[(wr * 64 + m * 16 + g * 4 + r) * 4 + wc] = part_rows[m][r];
    __syncthreads();
    if (tid < 128) {
      const float4 v = *(const float4*)&red[tid * 4];
      partials[(size_t)(bm0 + tid) * 64 + (bn0 >> 7)] = (v.x + v.y) + (v.z + v.w);
    }
  } else {
    float* C = (float*)Cv;
#pragma unroll
    for (int m = 0; m < 4; ++m)
#pragma unroll
      for (int r = 0; r < 4; ++r) {
        const int row = bm0 + wr * 64 + m * 16 + g * 4 + r;
        const float iv = inv ? inv[row] : 1.0f;
#pragma unroll
        for (int n = 0; n < 2; ++n)
          C[(size_t)row * ldc + c0 + n * 16] = acc[m][n][r] * iv;
      }
  }
}

// ---------------- inv[row] = 1 / sum_j partials[row][j] --------------------
__global__ __launch_bounds__(256) void rowinv(const float* __restrict__ partials,
                                              float* __restrict__ inv) {
  const int row = blockIdx.x * 256 + threadIdx.x;
  const float4* p = (const float4*)(partials + (size_t)row * 64);
  float s = 0.f;
#pragma unroll
  for (int j = 0; j < 16; ++j) {
    float4 v = p[j];
    s += (v.x + v.y) + (v.z + v.w);
  }
  inv[row] = 1.0f / s;
}

// --------------- fallback: normalize E rows in place (bf16) ----------------
__global__ __launch_bounds__(256) void normalize_inplace(u16* __restrict__ E) {
  __shared__ float red[4];
  u16* row = E + (size_t)blockIdx.x * 8192;
  const int tid = threadIdx.x;
  float f[32];
  float s = 0.f;
#pragma unroll
  for (int c = 0; c < 4; ++c) {
    uint4 v = *((const uint4*)row + c * 256 + tid);
    unsigned u[4] = {v.x, v.y, v.z, v.w};
#pragma unroll
    for (int q = 0; q < 4; ++q) {
      f[c * 8 + q * 2] = bf2f((u16)(u[q] & 0xffffu));
      f[c * 8 + q * 2 + 1] = bf2f((u16)(u[q] >> 16));
      s += f[c * 8 + q * 2] + f[c * 8 + q * 2 + 1];
    }
  }
#pragma unroll
  for (int off = 32; off; off >>= 1) s += __shfl_xor(s, off, 64);
  if ((tid & 63) == 0) red[tid >> 6] = s;
  __syncthreads();
  const float iv = 1.0f / ((red[0] + red[1]) + (red[2] + red[3]));
#pragma unroll
  for (int c = 0; c < 4; ++c) {
    uint4 o;
    o.x = pack2(f[c * 8 + 0] * iv, f[c * 8 + 1] * iv);
    o.y = pack2(f[c * 8 + 2] * iv, f[c * 8 + 3] * iv);
    o.z = pack2(f[c * 8 + 4] * iv, f[c * 8 + 5] * iv);
    o.w = pack2(f[c * 8 + 6] * iv, f[c * 8 + 7] * iv);
    *((uint4*)row + c * 256 + tid) = o;
  }
}

// ---------------------------------------------------------------------------
extern "C" void kernel_launch(void* const* d_in, const int* in_sizes, int n_in,
                              void* d_out, int out_size, void* d_ws, size_t ws_size,
                              hipStream_t stream) {
  const float* Q = (const float*)d_in[0];
  const float* K = (const float*)d_in[1];
  const float* V = (const float*)d_in[2];

  char* ws = (char*)d_ws;
  u16* S = (u16*)ws;                                              // 128 MB
  u16* VT = (u16*)(ws + (size_t)134217728);                       // 16 MB
  float* partials = (float*)(ws + (size_t)134217728 + 16777216);  // 2 MB used
  float* inv = (float*)(ws + (size_t)134217728 + 16777216 + 4194304);
  const bool haveInv =
      ws_size >= (size_t)134217728 + 16777216 + 4194304 + 32768;

  u16* Qb = (u16*)d_out;   // bf16 Q scratch (16 MB)
  u16* Kb = Qb + 8388608;  // bf16 K scratch (16 MB)

  cvt_bf16<<<4096, 256, 0, stream>>>(Q, Qb);
  cvt_bf16<<<4096, 256, 0, stream>>>(K, Kb);
  transpose_bf16<<<dim3(128, 16), 256, 0, stream>>>(V, VT);

  // E = exp(Q K^T / 32)  [8192 x 8192] bf16 ; grid 4096, 2 blocks/CU
  gemm2b<0, 0><<<4096, 512, 0, stream>>>(
      Qb, Kb, S, nullptr, haveInv ? partials : (float*)(ws + 134217728 + 16777216),
      1024, 8192, 1.0f / 32.0f);

  if (haveInv) {
    rowinv<<<32, 256, 0, stream>>>(partials, inv);
    // O = diag(inv) E V  [8192 x 1024] f32 ; grid 512, 2 blocks/CU
    gemm2b<1, 1><<<512, 512, 0, stream>>>(
        S, VT, d_out, inv, nullptr, 8192, 1024, 1.0f);
  } else {
    normalize_inplace<<<8192, 256, 0, stream>>>(S);
    gemm2b<1, 1><<<512, 512, 0, stream>>>(
        S, VT, d_out, nullptr, nullptr, 8192, 1024, 1.0f);
  }
}